// Round 5
// baseline (521.451 us; speedup 1.0000x reference)
//
#include <hip/hip_runtime.h>

#define NN 50000
#define NE 600000
#define DD 128
#define HR 260     // k_update LDS H row stride (elems)
#define EMAX 950016   // max padded slots: NE + 7*NN, rounded to /8
#define GMAX 118752   // EMAX/8 groups

typedef unsigned short u16;
typedef unsigned int   u32;
typedef u16   u16x8  __attribute__((ext_vector_type(8)));
typedef u16   u16x4  __attribute__((ext_vector_type(4)));
typedef u32   u32x4  __attribute__((ext_vector_type(4)));
typedef __bf16 bf16x8 __attribute__((ext_vector_type(8)));
typedef float f32x4  __attribute__((ext_vector_type(4)));

__device__ __forceinline__ u16 f2bf(float f) {  // RNE fp32->bf16
    unsigned u = __builtin_bit_cast(unsigned, f);
    u += 0x7FFFu + ((u >> 16) & 1u);
    return (u16)(u >> 16);
}
__device__ __forceinline__ float bf2f(u16 v) {
    return __builtin_bit_cast(float, (unsigned)v << 16);
}
__device__ __forceinline__ bf16x8 ldbf8(const u16* p) {
    return __builtin_bit_cast(bf16x8, *(const u16x8*)p);
}
__device__ __forceinline__ u32 pk2(float a, float b) {
    return (u32)f2bf(a) | ((u32)f2bf(b) << 16);
}

// Standard pack: W[K,N] fp32 row-major -> MFMA fragment order, frag = nt*(K/32)+kt
__device__ __forceinline__ void pack_elem(const float* __restrict__ W,
                                          u16* __restrict__ out, int tid, int K, int N) {
    int frag = tid >> 9, lane = (tid >> 3) & 63, j = tid & 7;
    int KT = K >> 5;
    int nt = frag / KT, kt = frag - nt * KT;
    int row = kt * 32 + ((lane >> 4) << 3) + j;
    int col = nt * 16 + (lane & 15);
    out[tid] = f2bf(W[row * N + col]);
}

// Fused prep: nf->bf16, zero agg/deg/cursor/P2-zero-row, pack Wcat, mW1, uW0, uW1.
__global__ __launch_bounds__(256) void k_prep(
    const float* __restrict__ nf, u16* __restrict__ nf16, float* __restrict__ agg,
    const float* __restrict__ mW0, u16* __restrict__ pWcat,
    const float* __restrict__ mW1, u16* __restrict__ pmW1,
    const float* __restrict__ uW0, u16* __restrict__ puW0,
    const float* __restrict__ uW1, u16* __restrict__ puW1,
    int* __restrict__ deg, int* __restrict__ cursor, u16* __restrict__ P2)
{
    int t = blockIdx.x * 256 + threadIdx.x;
    if (t < 1600000) {                       // NN*DD/4 float4 chunks
        float4 v = ((const float4*)nf)[t];
        u16x4 o; o[0] = f2bf(v.x); o[1] = f2bf(v.y); o[2] = f2bf(v.z); o[3] = f2bf(v.w);
        ((u16x4*)nf16)[t] = o;
        ((float4*)agg)[t] = make_float4(0.f, 0.f, 0.f, 0.f);
        return;
    }
    t -= 1600000;
    if (t < 65536) {   // Wcat: K=128, N=512
        int frag = t >> 9, lane = (t >> 3) & 63, j = t & 7;
        int nt = frag >> 2, kt = frag & 3;
        int rl = kt * 32 + ((lane >> 4) << 3) + j;
        int cl = lane & 15;
        int row = (nt < 16) ? rl : (128 + rl);
        int col = (nt < 16) ? (nt * 16 + cl) : ((nt - 16) * 16 + cl);
        pWcat[t] = f2bf(mW0[row * 256 + col]);
        return;
    }
    t -= 65536;
    if (t < 32768) { pack_elem(mW1, pmW1, t, 256, 128); return; }
    t -= 32768;
    if (t < 65536) { pack_elem(uW0, puW0, t, 256, 256); return; }
    t -= 65536;
    if (t < 32768) { pack_elem(uW1, puW1, t, 256, 128); return; }
    t -= 32768;
    if (t < 50000) {
        deg[t] = 0; cursor[t] = 0;
        if (t < 512) P2[(size_t)NN * 512 + t] = 0;   // zero row for dummy slots
    }
}

__global__ __launch_bounds__(256) void k_hist(const int* __restrict__ to_idx,
                                              int* __restrict__ deg) {
    int e = blockIdx.x * 256 + threadIdx.x;
    if (e < NE) atomicAdd(&deg[to_idx[e]], 1);
}

// Exclusive scan of padded degrees ((deg+7)&~7) -> poff[0..NN]; single block, wave scans.
__global__ __launch_bounds__(1024) void k_scan(const int* __restrict__ deg,
                                               int* __restrict__ poff) {
    __shared__ int wsum[16];
    __shared__ int carry;
    const int tid = threadIdx.x, lane = tid & 63, wv = tid >> 6;
    if (tid == 0) carry = 0;
    __syncthreads();
    for (int base = 0; base < NN; base += 1024) {
        int i = base + tid;
        int v = (i < NN) ? ((deg[i] + 7) & ~7) : 0;
        int x = v;
        #pragma unroll
        for (int off = 1; off < 64; off <<= 1) {
            int t = __shfl_up(x, off);
            if (lane >= off) x += t;
        }
        if (lane == 63) wsum[wv] = x;
        __syncthreads();
        if (wv == 0) {
            int s = (lane < 16) ? wsum[lane] : 0;
            #pragma unroll
            for (int off = 1; off < 16; off <<= 1) {
                int t = __shfl_up(s, off);
                if (lane >= off) s += t;
            }
            if (lane < 16) wsum[lane] = s;   // inclusive wave bases
        }
        __syncthreads();
        int wbase = (wv > 0) ? wsum[wv - 1] : 0;
        if (i < NN) poff[i] = carry + wbase + x - v;
        __syncthreads();
        if (tid == 1023) carry += wsum[15];
        __syncthreads();
    }
    if (threadIdx.x == 0) poff[NN] = carry;
}

__global__ __launch_bounds__(256) void k_groups(const int* __restrict__ poff,
                                                int* __restrict__ gnode) {
    int n = blockIdx.x * 256 + threadIdx.x;
    if (n >= NN) return;
    int a = poff[n] >> 3, b = poff[n + 1] >> 3;
    for (int g = a; g < b; ++g) gnode[g] = n;
}

__global__ __launch_bounds__(256) void k_scatter(
    const int* __restrict__ from_idx, const int* __restrict__ to_idx,
    const int* __restrict__ poff, int* __restrict__ cursor,
    int* __restrict__ slot_from) {
    int e = blockIdx.x * 256 + threadIdx.x;
    if (e >= NE) return;
    int to = to_idx[e];
    int r = atomicAdd(&cursor[to], 1);
    slot_from[poff[to] + r] = from_idx[e];
}

// P2[n][0:256]  = nf[n].W0top + b0 ; P2[n][256:512] = nf[n].W0bot
__global__ __launch_bounds__(192, 4) void k_pgemm(
    const u16* __restrict__ nf16, const float* __restrict__ mb0,
    const u16* __restrict__ pWcat, u16* __restrict__ P2)
{
    const int tid = threadIdx.x;
    const int wave = tid >> 6, lane = tid & 63;
    const int l15 = lane & 15, quad = lane >> 4;
    const int nb = blockIdx.x * 96 + wave * 32;
    const int co = quad * 8;

    bf16x8 x[2][4];
    #pragma unroll
    for (int m = 0; m < 2; ++m) {
        int node = nb + m * 16 + l15;
        int cn = (node < NN) ? node : 0;
        #pragma unroll
        for (int kt = 0; kt < 4; ++kt)
            x[m][kt] = ldbf8(nf16 + (size_t)cn * DD + kt * 32 + co);
    }
    for (int nt = 0; nt < 32; ++nt) {
        const u16* wp = pWcat + nt * 4 * 512 + lane * 8;
        f32x4 c0 = {0.f,0.f,0.f,0.f}, c1 = {0.f,0.f,0.f,0.f};
        #pragma unroll
        for (int kt = 0; kt < 4; ++kt) {
            bf16x8 b = ldbf8(wp + kt * 512);
            c0 = __builtin_amdgcn_mfma_f32_16x16x32_bf16(x[0][kt], b, c0, 0, 0, 0);
            c1 = __builtin_amdgcn_mfma_f32_16x16x32_bf16(x[1][kt], b, c1, 0, 0, 0);
        }
        float bias = (nt < 16) ? mb0[nt * 16 + l15] : 0.f;
        #pragma unroll
        for (int i = 0; i < 4; ++i) {
            int r0 = nb + quad * 4 + i;
            int r1 = nb + 16 + quad * 4 + i;
            if (r0 < NN) P2[(size_t)r0 * 512 + nt * 16 + l15] = f2bf(c0[i] + bias);
            if (r1 < NN) P2[(size_t)r1 * 512 + nt * 16 + l15] = f2bf(c1[i] + bias);
        }
    }
}

// Message+aggregate: wave handles 4 groups (32 slots); group = 8 slots of one
// to-node -> in-register segment sum, 1 atomic per group per feature.
__global__ __launch_bounds__(192, 3) void k_msg(
    const u16* __restrict__ P2, const int* __restrict__ slot_from,
    const int* __restrict__ gnode, const u16* __restrict__ pW1,
    const float* __restrict__ b1, float* __restrict__ agg)
{
    const int tid = threadIdx.x;
    const int wave = tid >> 6, lane = tid & 63;
    const int l15 = lane & 15, quad = lane >> 4;
    const int wgid = blockIdx.x * 3 + wave;
    const int G0 = wgid * 4;
    const int co = quad * 8;

    const int nCq = gnode[G0 + quad];        // C-side group node (per quad)
    if (__all(nCq < 0)) return;              // dead tail waves exit fast

    // A-side: row r = m*16 + l15; group = G0 + (l15>>2); slot = m*4 + (l15&3)
    const int gA = G0 + (l15 >> 2);
    const int nA = gnode[gA];
    const int rowT = (nA < 0) ? NN : nA;
    const int sA0 = gA * 8 + (l15 & 3);
    const int fr0 = slot_from[sA0];
    const int fr1 = slot_from[sA0 + 4];
    const int rF0 = (fr0 < 0) ? NN : fr0;
    const int rF1 = (fr1 < 0) ? NN : fr1;

    const u16* pT  = P2 + (size_t)rowT * 512 + 256 + co;
    const u16* pF0 = P2 + (size_t)rF0 * 512 + co;
    const u16* pF1 = P2 + (size_t)rF1 * 512 + co;

    f32x4 acc[2][8];
    #pragma unroll
    for (int m = 0; m < 2; ++m)
        #pragma unroll
        for (int n = 0; n < 8; ++n) acc[m][n] = (f32x4){0.f, 0.f, 0.f, 0.f};

    u16x8 ta = *(const u16x8*)pT;
    u16x8 a0 = *(const u16x8*)pF0;
    u16x8 a1 = *(const u16x8*)pF1;

    #pragma unroll
    for (int kt = 0; kt < 8; ++kt) {
        u16x8 nta, na0, na1;
        if (kt < 7) {
            int o = (kt + 1) * 32;
            nta = *(const u16x8*)(pT + o);
            na0 = *(const u16x8*)(pF0 + o);
            na1 = *(const u16x8*)(pF1 + o);
        }
        u32x4 q0, q1;
        #pragma unroll
        for (int e = 0; e < 4; ++e) {
            float t0 = bf2f(ta[2*e]), t1 = bf2f(ta[2*e+1]);
            q0[e] = pk2(fmaxf(bf2f(a0[2*e]) + t0, 0.f), fmaxf(bf2f(a0[2*e+1]) + t1, 0.f));
            q1[e] = pk2(fmaxf(bf2f(a1[2*e]) + t0, 0.f), fmaxf(bf2f(a1[2*e+1]) + t1, 0.f));
        }
        bf16x8 h0 = __builtin_bit_cast(bf16x8, q0);
        bf16x8 h1 = __builtin_bit_cast(bf16x8, q1);
        const u16* wp = pW1 + kt * 512 + lane * 8;
        #pragma unroll
        for (int n = 0; n < 8; ++n) {
            bf16x8 w = ldbf8(wp + n * 4096);
            acc[0][n] = __builtin_amdgcn_mfma_f32_16x16x32_bf16(h0, w, acc[0][n], 0, 0, 0);
            acc[1][n] = __builtin_amdgcn_mfma_f32_16x16x32_bf16(h1, w, acc[1][n], 0, 0, 0);
        }
        ta = nta; a0 = na0; a1 = na1;
    }

    // C-side validity: row m*16+quad*4+i -> slot (G0+quad)*8 + m*4 + i
    const int sC = (G0 + quad) * 8;
    int fv[2][4];
    #pragma unroll
    for (int m = 0; m < 2; ++m)
        #pragma unroll
        for (int i = 0; i < 4; ++i)
            fv[m][i] = slot_from[sC + m * 4 + i];

    if (nCq < 0) return;   // per-quad? no: nCq<0 implies all its slots dummy; but exec
                           // mask here is per-lane and quads differ -> guard the store below instead.

    #pragma unroll
    for (int n = 0; n < 8; ++n) {
        float bs = b1[n * 16 + l15];
        float tot = 0.f;
        #pragma unroll
        for (int m = 0; m < 2; ++m)
            #pragma unroll
            for (int i = 0; i < 4; ++i)
                if (fv[m][i] >= 0) tot += fmaxf(acc[m][n][i] + bs, 0.f);
        unsafeAtomicAdd(agg + (size_t)nCq * DD + n * 16 + l15, tot);
    }
}

// Node update: out = nf + relu(relu([agg|nf] uW0 + ub0) uW1 + ub1)
__global__ __launch_bounds__(128, 3) void k_update(
    const float* __restrict__ agg, const u16* __restrict__ nf16,
    const float* __restrict__ nf32, const u16* __restrict__ pW0,
    const float* __restrict__ b0, const u16* __restrict__ pW1,
    const float* __restrict__ b1, float* __restrict__ out)
{
    __shared__ u16 sH[2 * 32 * HR];
    const int tid = threadIdx.x;
    const int wave = tid >> 6, lane = tid & 63;
    const int l15 = lane & 15, quad = lane >> 4;
    const int n0 = blockIdx.x * 64 + wave * 32;
    const int co = quad * 8;

    bf16x8 x[2][8];
    #pragma unroll
    for (int m = 0; m < 2; ++m) {
        int node = n0 + m * 16 + l15;
        int cn = (node < NN) ? node : 0;
        #pragma unroll
        for (int kt = 0; kt < 4; ++kt) {
            const float* p = agg + (size_t)cn * DD + kt * 32 + co;
            float4 u = *(const float4*)p;
            float4 v = *(const float4*)(p + 4);
            u32x4 q;
            q[0] = pk2(u.x, u.y); q[1] = pk2(u.z, u.w);
            q[2] = pk2(v.x, v.y); q[3] = pk2(v.z, v.w);
            x[m][kt] = __builtin_bit_cast(bf16x8, q);
        }
        #pragma unroll
        for (int kt = 0; kt < 4; ++kt)
            x[m][4 + kt] = ldbf8(nf16 + (size_t)cn * DD + kt * 32 + co);
    }

    u16* myH = sH + wave * 32 * HR;
    for (int nt = 0; nt < 16; ++nt) {
        const u16* wp = pW0 + nt * 8 * 512 + lane * 8;
        f32x4 c0 = {0.f,0.f,0.f,0.f}, c1 = {0.f,0.f,0.f,0.f};
        #pragma unroll
        for (int kt = 0; kt < 8; ++kt) {
            bf16x8 b = ldbf8(wp + kt * 512);
            c0 = __builtin_amdgcn_mfma_f32_16x16x32_bf16(x[0][kt], b, c0, 0, 0, 0);
            c1 = __builtin_amdgcn_mfma_f32_16x16x32_bf16(x[1][kt], b, c1, 0, 0, 0);
        }
        float bias = b0[nt * 16 + l15];
        #pragma unroll
        for (int i = 0; i < 4; ++i) {
            myH[(quad * 4 + i) * HR + nt * 16 + l15]      = f2bf(fmaxf(c0[i] + bias, 0.f));
            myH[(16 + quad * 4 + i) * HR + nt * 16 + l15] = f2bf(fmaxf(c1[i] + bias, 0.f));
        }
    }
    for (int n = 0; n < 8; ++n) {
        f32x4 c0 = {0.f,0.f,0.f,0.f}, c1 = {0.f,0.f,0.f,0.f};
        #pragma unroll
        for (int kt = 0; kt < 8; ++kt) {
            const u16* h0p = myH + l15 * HR + kt * 32 + co;
            const u16* h1p = myH + (16 + l15) * HR + kt * 32 + co;
            u16x4 a0 = *(const u16x4*)h0p;
            u16x4 a1 = *(const u16x4*)(h0p + 4);
            u16x4 b0v = *(const u16x4*)h1p;
            u16x4 b1v = *(const u16x4*)(h1p + 4);
            u16x8 hh0, hh1;
            hh0[0]=a0[0]; hh0[1]=a0[1]; hh0[2]=a0[2]; hh0[3]=a0[3];
            hh0[4]=a1[0]; hh0[5]=a1[1]; hh0[6]=a1[2]; hh0[7]=a1[3];
            hh1[0]=b0v[0]; hh1[1]=b0v[1]; hh1[2]=b0v[2]; hh1[3]=b0v[3];
            hh1[4]=b1v[0]; hh1[5]=b1v[1]; hh1[6]=b1v[2]; hh1[7]=b1v[3];
            bf16x8 b = ldbf8(pW1 + (n * 8 + kt) * 512 + lane * 8);
            c0 = __builtin_amdgcn_mfma_f32_16x16x32_bf16(__builtin_bit_cast(bf16x8, hh0), b, c0, 0, 0, 0);
            c1 = __builtin_amdgcn_mfma_f32_16x16x32_bf16(__builtin_bit_cast(bf16x8, hh1), b, c1, 0, 0, 0);
        }
        float bias = b1[n * 16 + l15];
        #pragma unroll
        for (int i = 0; i < 4; ++i) {
            int r0 = n0 + quad * 4 + i;
            int r1 = n0 + 16 + quad * 4 + i;
            if (r0 < NN) {
                int idx = r0 * DD + n * 16 + l15;
                out[idx] = nf32[idx] + fmaxf(c0[i] + bias, 0.f);
            }
            if (r1 < NN) {
                int idx = r1 * DD + n * 16 + l15;
                out[idx] = nf32[idx] + fmaxf(c1[i] + bias, 0.f);
            }
        }
    }
}

extern "C" void kernel_launch(void* const* d_in, const int* in_sizes, int n_in,
                              void* d_out, int out_size, void* d_ws, size_t ws_size,
                              hipStream_t stream)
{
    const float* nf  = (const float*)d_in[0];
    const int* fidx  = (const int*)d_in[1];
    const int* tidx  = (const int*)d_in[2];
    const float* mW0 = (const float*)d_in[3];
    const float* mb0 = (const float*)d_in[4];
    const float* mW1 = (const float*)d_in[5];
    const float* mb1 = (const float*)d_in[6];
    const float* uW0 = (const float*)d_in[7];
    const float* ub0 = (const float*)d_in[8];
    const float* uW1 = (const float*)d_in[9];
    const float* ub1 = (const float*)d_in[10];
    float* out = (float*)d_out;

    char* ws = (char*)d_ws;
    u16*   nf16  = (u16*)ws;   ws += (size_t)NN * DD * 2;          // 12.8 MB
    float* agg   = (float*)ws; ws += (size_t)NN * DD * 4;          // 25.6 MB
    u16*   P2    = (u16*)ws;   ws += (size_t)(NN + 1) * 512 * 2;   // 51.2 MB (+zero row)
    u16*   pWcat = (u16*)ws;   ws += 128 * 512 * 2;
    u16*   pmW1  = (u16*)ws;   ws += 256 * 128 * 2;
    u16*   puW0  = (u16*)ws;   ws += 256 * 256 * 2;
    u16*   puW1  = (u16*)ws;   ws += 256 * 128 * 2;
    int*   deg   = (int*)ws;   ws += NN * 4;
    int*   cursor= (int*)ws;   ws += NN * 4;
    int*   poff  = (int*)ws;   ws += (NN + 4) * 4;
    int*   slot_from = (int*)ws; ws += (size_t)EMAX * 4;           // 3.8 MB
    int*   gnode = (int*)ws;   ws += (size_t)GMAX * 4;             // 0.5 MB

    hipMemsetAsync(slot_from, 0xFF, (size_t)EMAX * 4, stream);
    hipMemsetAsync(gnode, 0xFF, (size_t)GMAX * 4, stream);
    // 1,600,000 + 196,608 + 50,000 threads
    k_prep<<<7214, 256, 0, stream>>>(nf, nf16, agg, mW0, pWcat, mW1, pmW1,
                                     uW0, puW0, uW1, puW1, deg, cursor, P2);
    k_hist<<<2344, 256, 0, stream>>>(tidx, deg);
    k_scan<<<1, 1024, 0, stream>>>(deg, poff);
    k_groups<<<196, 256, 0, stream>>>(poff, gnode);
    k_scatter<<<2344, 256, 0, stream>>>(fidx, tidx, poff, cursor, slot_from);
    k_pgemm<<<(NN + 95) / 96, 192, 0, stream>>>(nf16, mb0, pWcat, P2);
    k_msg<<<GMAX / 12, 192, 0, stream>>>(P2, slot_from, gnode, pmW1, mb1, agg);
    k_update<<<(NN + 63) / 64, 128, 0, stream>>>(agg, nf16, nf, puW0, ub0, puW1, ub1, out);
}